// Round 8
// baseline (140.275 us; speedup 1.0000x reference)
//
#include <hip/hip_runtime.h>
#include <math.h>

typedef _Float16 f16;
typedef f16   f16x4    __attribute__((ext_vector_type(4)));
typedef float floatx2  __attribute__((ext_vector_type(2)));
typedef float floatx4  __attribute__((ext_vector_type(4)));
typedef float floatx16 __attribute__((ext_vector_type(16)));

#define LOG2E   1.44269504088896340736f
#define INV_2PI 0.15915494309189533577f

// Problem constants
#define B_SZ  2048
#define DIN   64
#define DOUT  64
#define NH    32

// ---- packed-f32 (VOP3P) helpers (instruction-count halving) ----
__device__ __forceinline__ floatx2 pk_add(floatx2 a, floatx2 b) {
    floatx2 d; asm("v_pk_add_f32 %0, %1, %2" : "=v"(d) : "v"(a), "v"(b)); return d;
}
__device__ __forceinline__ floatx2 pk_mul(floatx2 a, floatx2 b) {
    floatx2 d; asm("v_pk_mul_f32 %0, %1, %2" : "=v"(d) : "v"(a), "v"(b)); return d;
}
__device__ __forceinline__ floatx2 pk_fma(floatx2 a, floatx2 b, floatx2 c) {
    floatx2 d; asm("v_pk_fma_f32 %0, %1, %2, %3" : "=v"(d) : "v"(a), "v"(b), "v"(c)); return d;
}

// 16B load with only 4B alignment guarantee (W1 rows stride 28B)
__device__ __forceinline__ floatx4 load4u(const float* p) {
    floatx4 v; __builtin_memcpy(&v, p, 16); return v;
}

// A-frag pack: lane<32 -> {f0,f1,f2,f3}; lane>=32 -> {f4,f5,f6,B1}
// (input w = W1[i][o][h][hi?3..6:0..3] via shifted load), scaled by -log2e.
__device__ __forceinline__ f16x4 packA(floatx4 w, float b1v, bool hi) {
    float g0 = (hi ? w[1] : w[0]) * (-LOG2E);
    float g1 = (hi ? w[2] : w[1]) * (-LOG2E);
    float g2 = (hi ? w[3] : w[2]) * (-LOG2E);
    float g3 = (hi ? b1v  : w[3]) * (-LOG2E);
    return (f16x4){(f16)g0, (f16)g1, (f16)g2, (f16)g3};
}

// silu over 8 activations (2 r-groups in pk lanes x 4-deep batched-rcp tree),
// 8-way combined reciprocal: ONE rcp per 8 activations.
// d_i = 1 + 2^(a''_i) = 1 + e^{-a_i};  u_i = a''_i * w_i  (w = RAW W2 here;
// the -log2e / -1/log2e scales cancel via one final multiply in the epilogue)
__device__ __forceinline__ void silu8(
        floatx2 A0, floatx2 A1, floatx2 A2, floatx2 A3,
        floatx2 W0, floatx2 W1, floatx2 W2, floatx2 W3,
        floatx2 one2, float& phi) {
    floatx2 E0 = {__builtin_amdgcn_exp2f(A0[0]), __builtin_amdgcn_exp2f(A0[1])};
    floatx2 E1 = {__builtin_amdgcn_exp2f(A1[0]), __builtin_amdgcn_exp2f(A1[1])};
    floatx2 E2 = {__builtin_amdgcn_exp2f(A2[0]), __builtin_amdgcn_exp2f(A2[1])};
    floatx2 E3 = {__builtin_amdgcn_exp2f(A3[0]), __builtin_amdgcn_exp2f(A3[1])};
    floatx2 D0 = pk_add(E0, one2), D1 = pk_add(E1, one2);
    floatx2 D2 = pk_add(E2, one2), D3 = pk_add(E3, one2);
    floatx2 U0 = pk_mul(A0, W0), U1 = pk_mul(A1, W1);
    floatx2 U2 = pk_mul(A2, W2), U3 = pk_mul(A3, W3);
    floatx2 N01 = pk_fma(U0, D1, pk_mul(U1, D0));
    floatx2 N23 = pk_fma(U2, D3, pk_mul(U3, D2));
    floatx2 P01 = pk_mul(D0, D1), P23 = pk_mul(D2, D3);
    floatx2 N   = pk_fma(N01, P23, pk_mul(N23, P01));
    floatx2 DD  = pk_mul(P01, P23);
    float n8 = __builtin_fmaf(N[0], DD[1], N[1] * DD[0]);
    float d8 = DD[0] * DD[1];
    phi = __builtin_fmaf(n8, __builtin_amdgcn_rcpf(d8), phi);
}

// ---------------------------------------------------------------------------
// FUSED single kernel, ZERO workspace. grid = 16 og x 64 btp = 1024 blocks,
// block = 256 (4 waves). Wave wv -> o = og*4+wv; full i = 0..63 per wave ->
// each (b,o) written exactly once (plain store, no atomics, no zeroing).
// Setup: feature B-frags (sincos via HW v_sin/v_cos, double-angle chain)
// for all 64 i x 64 lanes into 32 KB LDS (8 sincos per thread, once).
// Loop: A-frag built on the fly from raw W1/B1 (shifted 16B load + cndmask
// select + scale + cvt); W2 read RAW from global (L2-hot broadcast); ONE
// mfma_32x32x8 issued one iteration ahead of the silu that consumes it;
// all loads prefetched one iteration ahead. Epilogue: phi * (-1/log2e)
// (scale cancellation) + column-sum of B2, direct store to out.
// ---------------------------------------------------------------------------
__global__ __launch_bounds__(256, 4) void fused_kernel(
        const float* __restrict__ x,  const float* __restrict__ W1,
        const float* __restrict__ B1, const float* __restrict__ W2,
        const float* __restrict__ B2, float* __restrict__ out) {
    const int tid  = threadIdx.x;
    const int lane = tid & 63;
    const int wv   = tid >> 6;
    const int btp  = blockIdx.x & 63;
    const int og   = blockIdx.x >> 6;
    const int o    = __builtin_amdgcn_readfirstlane(og * 4 + wv);
    const int h    = lane & 31;
    const bool hi  = lane >= 32;

    // feature LDS: flds[i][n*4] f16, n = lane position (n<32: {x,s1,s2,s4},
    // n>=32: {c1,c2,c4,1} of x[btp*32 + (n&31)][i]). 64 rows x 512 B = 32 KB.
    __shared__ f16 flds[64][256];

    {   // setup: thread t -> row b = btp*32 + (t>>3), i-range (t&7)*8..+7
        int bl = tid >> 3, i0 = (tid & 7) * 8;
        const float* xp = x + ((size_t)(btp * 32 + bl)) * 64 + i0;
        floatx4 xa = *(const floatx4*)xp;
        floatx4 xb = *(const floatx4*)(xp + 4);
#pragma unroll
        for (int k = 0; k < 8; ++k) {
            float xv = k < 4 ? xa[k & 3] : xb[k & 3];
            float xr = xv * INV_2PI;
            float s1 = __builtin_amdgcn_sinf(xr);
            float c1 = __builtin_amdgcn_cosf(xr);
            float s2 = 2.0f * s1 * c1, c2 = 1.0f - 2.0f * s1 * s1;
            float s4 = 2.0f * s2 * c2, c4 = 1.0f - 2.0f * s2 * s2;
            f16x4 vlo = {(f16)xv, (f16)s1, (f16)s2, (f16)s4};
            f16x4 vhi = {(f16)c1, (f16)c2, (f16)c4, (f16)1.0f};
            int i = i0 + k;
            *(f16x4*)&flds[i][bl * 4]        = vlo;
            *(f16x4*)&flds[i][(bl + 32) * 4] = vhi;
        }
    }
    __syncthreads();

    // per-lane base pointers (per-i strides: W1 14336, B1/W2 2048 floats)
    const float* w1p = W1 + (size_t)(o * 32 + h) * 7 + (hi ? 3 : 0);
    const float* b1p = B1 + o * 32 + h;
    const float* w2p = W2 + (size_t)o * 32 + (hi ? 4 : 0);

    const floatx16 zeroC = {};
    const floatx2  one2  = {1.0f, 1.0f};
    float phiL = 0.0f, phiH = 0.0f;

    // prologue: frag(0) -> C0; raw(1) + w2(0),w2(1) staged
    floatx4 rw  = load4u(w1p);
    float   rb  = *b1p;
    f16x4   rbf = *(const f16x4*)&flds[0][lane * 4];
    floatx4 w2c0 = *(const floatx4*)(w2p);
    floatx4 w2c1 = *(const floatx4*)(w2p + 8);
    floatx4 w2c2 = *(const floatx4*)(w2p + 16);
    floatx4 w2c3 = *(const floatx4*)(w2p + 24);
    floatx16 C0 = __builtin_amdgcn_mfma_f32_32x32x8f16(packA(rw, rb, hi), rbf, zeroC, 0, 0, 0);
    rw  = load4u(w1p + 14336);
    rb  = b1p[2048];
    rbf = *(const f16x4*)&flds[1][lane * 4];
    floatx4 w2n0 = *(const floatx4*)(w2p + 2048);
    floatx4 w2n1 = *(const floatx4*)(w2p + 2048 + 8);
    floatx4 w2n2 = *(const floatx4*)(w2p + 2048 + 16);
    floatx4 w2n3 = *(const floatx4*)(w2p + 2048 + 24);

#pragma unroll 1
    for (int ii = 0; ii < 64; ++ii) {
        // issue next MFMA before consuming C0 (ii=63's result is discarded)
        floatx16 C1 = __builtin_amdgcn_mfma_f32_32x32x8f16(packA(rw, rb, hi), rbf, zeroC, 0, 0, 0);

        // prefetch raw(ii+2), clamped (tail re-reads row 63; never OOB)
        const size_t inx = (size_t)(ii + 2 <= 63 ? ii + 2 : 63);
        rw  = load4u(w1p + inx * 14336);
        rb  = b1p[inx * 2048];
        rbf = *(const f16x4*)&flds[inx][lane * 4];

        // silu on C0 with w2(ii); lo half r=0,1 ; hi half r=2,3
        silu8((floatx2){C0[0],  C0[1]},  (floatx2){C0[4],  C0[5]},
              (floatx2){C0[8],  C0[9]},  (floatx2){C0[12], C0[13]},
              (floatx2){w2c0[0], w2c0[1]}, (floatx2){w2c1[0], w2c1[1]},
              (floatx2){w2c2[0], w2c2[1]}, (floatx2){w2c3[0], w2c3[1]},
              one2, phiL);
        silu8((floatx2){C0[2],  C0[3]},  (floatx2){C0[6],  C0[7]},
              (floatx2){C0[10], C0[11]}, (floatx2){C0[14], C0[15]},
              (floatx2){w2c0[2], w2c0[3]}, (floatx2){w2c1[2], w2c1[3]},
              (floatx2){w2c2[2], w2c2[3]}, (floatx2){w2c3[2], w2c3[3]},
              one2, phiH);

        // rotate w2 pipeline and prefetch w2(ii+2)
        w2c0 = w2n0; w2c1 = w2n1; w2c2 = w2n2; w2c3 = w2n3;
        w2n0 = *(const floatx4*)(w2p + inx * 2048);
        w2n1 = *(const floatx4*)(w2p + inx * 2048 + 8);
        w2n2 = *(const floatx4*)(w2p + inx * 2048 + 16);
        w2n3 = *(const floatx4*)(w2p + inx * 2048 + 24);

        C0 = C1;
    }

    float phi = phiL + phiH;
    // combine the two row-halves (lane and lane^32 share the same column)
    phi += __shfl_xor(phi, 32, 64);

    if (lane < 32) {
        // scale cancellation: accumulated phi = -log2e * sum(a*W2*sigma)
        float b2s = 0.0f;
#pragma unroll 1
        for (int i2 = 0; i2 < 64; ++i2) b2s += B2[i2 * 64 + o];
        out[((size_t)btp * 32 + lane) * 64 + o] = phi * (-1.0f / LOG2E) + b2s;
    }
}

extern "C" void kernel_launch(void* const* d_in, const int* in_sizes, int n_in,
                              void* d_out, int out_size, void* d_ws, size_t ws_size,
                              hipStream_t stream) {
    const float* x  = (const float*)d_in[0];
    const float* W1 = (const float*)d_in[1];
    const float* W2 = (const float*)d_in[2];
    const float* B1 = (const float*)d_in[3];
    const float* B2 = (const float*)d_in[4];
    float* out = (float*)d_out;
    (void)d_ws; (void)ws_size;   // zero workspace use

    fused_kernel<<<16 * 64, 256, 0, stream>>>(x, W1, B1, W2, B2, out);
}

// Round 9
// 111.821 us; speedup vs baseline: 1.2545x; 1.2545x over previous
//
#include <hip/hip_runtime.h>
#include <math.h>

typedef _Float16 f16;
typedef f16   f16x4    __attribute__((ext_vector_type(4)));
typedef f16   f16x8    __attribute__((ext_vector_type(8)));
typedef float floatx2  __attribute__((ext_vector_type(2)));
typedef float floatx4  __attribute__((ext_vector_type(4)));
typedef float floatx16 __attribute__((ext_vector_type(16)));

#define LOG2E   1.44269504088896340736f
#define INV_2PI 0.15915494309189533577f

// Problem constants
#define B_SZ  2048
#define DIN   64
#define DOUT  64
#define NH    32

#define NIG   4                 // i-groups (8192 blocks)
#define IGW   (DIN / NIG)       // 16 i per block

// Images (built by prep_kernel), K=8-packed for mfma_32x32x8:
//  w1img f16 [i][o][lane(64)][j(4)]: A-frag, m=h=lane&31, k=(lane>>5)*4+j.
//        lane<32 -> k=0..3 -> W1[...,{x,s1,s2,s4}]; lane>=32 -> k=4..7 ->
//        {W1[4],W1[5],W1[6],B1} (bias via constant-1 feature). Scaled by -log2e.
//  fimg  f16 [i][btp(64)][lane(64)][j(4)]: B-frag, n=b=lane&31, k as above;
//        lane<32 -> {x,s1,s2,s4}; lane>=32 -> {c1,c2,c4,1}.
//  b2sum f32 [64]: column sums of B2.
//  (W2 is consumed RAW by main; the -log2e scale on the images cancels via
//   one multiply in main's epilogue: phi_true = phi_acc * (-1/log2e).)
#define W1IMG_ELEMS ((size_t)DIN * DOUT * 64 * 4)   // 1,048,576 f16 = 2 MB
#define FIMG_ELEMS  ((size_t)DIN * 64 * 64 * 4)     // 1,048,576 f16 = 2 MB

// ---- packed-f32 (VOP3P) helpers (instruction-count halving) ----
__device__ __forceinline__ floatx2 pk_add(floatx2 a, floatx2 b) {
    floatx2 d; asm("v_pk_add_f32 %0, %1, %2" : "=v"(d) : "v"(a), "v"(b)); return d;
}
__device__ __forceinline__ floatx2 pk_mul(floatx2 a, floatx2 b) {
    floatx2 d; asm("v_pk_mul_f32 %0, %1, %2" : "=v"(d) : "v"(a), "v"(b)); return d;
}
__device__ __forceinline__ floatx2 pk_fma(floatx2 a, floatx2 b, floatx2 c) {
    floatx2 d; asm("v_pk_fma_f32 %0, %1, %2, %3" : "=v"(d) : "v"(a), "v"(b), "v"(c)); return d;
}

// ---------------------------------------------------------------------------
// prep: bid [0,512) -> w1img, [512,1024) -> fimg, [1024,1152) -> zero out[],
// 1152 -> b2sum. sin/cos via HW v_sin/v_cos (revolutions; |x|/2pi < 0.8).
// ---------------------------------------------------------------------------
__global__ __launch_bounds__(256) void prep_kernel(
        const float* __restrict__ W1, const float* __restrict__ B1,
        const float* __restrict__ B2, const float* __restrict__ x,
        f16* __restrict__ w1img, f16* __restrict__ fimg,
        float* __restrict__ b2sum, float* __restrict__ out) {
    const int bid = blockIdx.x, tid = threadIdx.x;
    if (bid < 512) {
        int u = bid * 256 + tid;             // [i][o][lane2] lane2 = lane pair
        int lane2 = u & 31, o = (u >> 5) & 63, i = u >> 11;
        int l0 = lane2 * 2;
        f16x8 v;
        if (lane2 < 16) {                    // rows l0,l0+1; k=0..3 -> w[0..3]
#pragma unroll
            for (int t = 0; t < 2; ++t) {
                const float* w = W1 + (size_t)((i * 64 + o) * 32 + l0 + t) * 7;
#pragma unroll
                for (int j = 0; j < 4; ++j) v[t * 4 + j] = (f16)(w[j] * (-LOG2E));
            }
        } else {                             // rows l0-32,l0-31; k=4..7 -> w[4..6],B1
#pragma unroll
            for (int t = 0; t < 2; ++t) {
                int m = l0 - 32 + t;
                const float* w = W1 + (size_t)((i * 64 + o) * 32 + m) * 7;
                v[t * 4 + 0] = (f16)(w[4] * (-LOG2E));
                v[t * 4 + 1] = (f16)(w[5] * (-LOG2E));
                v[t * 4 + 2] = (f16)(w[6] * (-LOG2E));
                v[t * 4 + 3] = (f16)(B1[(i * 64 + o) * 32 + m] * (-LOG2E));
            }
        }
        *(f16x8*)(w1img + (size_t)u * 8) = v;
    } else if (bid < 1024) {
        int u = (bid - 512) * 256 + tid;     // [i][btp][lane2]
        int lane2 = u & 31, btp = (u >> 5) & 63, i = u >> 11;
        int l0 = lane2 * 2;
        f16x8 v;
#pragma unroll
        for (int t = 0; t < 2; ++t) {
            int b = btp * 32 + ((l0 + t) & 31);
            float xv = x[b * 64 + i];
            float s1 = __builtin_amdgcn_sinf(xv * INV_2PI);
            float c1 = __builtin_amdgcn_cosf(xv * INV_2PI);
            float s2 = 2.0f * s1 * c1, c2 = 1.0f - 2.0f * s1 * s1;
            float s4 = 2.0f * s2 * c2, c4 = 1.0f - 2.0f * s2 * s2;
            if (lane2 < 16) { v[t*4+0] = (f16)xv; v[t*4+1] = (f16)s1;
                              v[t*4+2] = (f16)s2; v[t*4+3] = (f16)s4; }
            else            { v[t*4+0] = (f16)c1; v[t*4+1] = (f16)c2;
                              v[t*4+2] = (f16)c4; v[t*4+3] = (f16)1.0f; }
        }
        *(f16x8*)(fimg + (size_t)u * 8) = v;
    } else if (bid < 1152) {
        int t = (bid - 1024) * 256 + tid;    // zero out[] (atomics accumulate)
        floatx4 z = {};
        *(floatx4*)(out + (size_t)t * 4) = z;
    } else if (tid < 64) {
        float s = 0.0f;
        for (int i = 0; i < 64; ++i) s += B2[i * 64 + tid];
        b2sum[tid] = s;
    }
}

// silu over 8 activations (2 r-groups in pk lanes x 4-deep batched-rcp tree),
// 8-way combined reciprocal: ONE rcp per 8 activations.
//   d_i = 1 + 2^(a''_i),  u_i = a''_i * W2raw_i  (a'' = -log2e*a; the scale
//   cancels via phi * (-1/log2e) in the epilogue)
__device__ __forceinline__ void silu8(
        floatx2 A0, floatx2 A1, floatx2 A2, floatx2 A3,
        floatx2 W0, floatx2 W1, floatx2 W2, floatx2 W3,
        floatx2 one2, float& phi) {
    floatx2 E0 = {__builtin_amdgcn_exp2f(A0[0]), __builtin_amdgcn_exp2f(A0[1])};
    floatx2 E1 = {__builtin_amdgcn_exp2f(A1[0]), __builtin_amdgcn_exp2f(A1[1])};
    floatx2 E2 = {__builtin_amdgcn_exp2f(A2[0]), __builtin_amdgcn_exp2f(A2[1])};
    floatx2 E3 = {__builtin_amdgcn_exp2f(A3[0]), __builtin_amdgcn_exp2f(A3[1])};
    floatx2 D0 = pk_add(E0, one2), D1 = pk_add(E1, one2);
    floatx2 D2 = pk_add(E2, one2), D3 = pk_add(E3, one2);
    floatx2 U0 = pk_mul(A0, W0), U1 = pk_mul(A1, W1);
    floatx2 U2 = pk_mul(A2, W2), U3 = pk_mul(A3, W3);
    floatx2 N01 = pk_fma(U0, D1, pk_mul(U1, D0));
    floatx2 N23 = pk_fma(U2, D3, pk_mul(U3, D2));
    floatx2 P01 = pk_mul(D0, D1), P23 = pk_mul(D2, D3);
    floatx2 N   = pk_fma(N01, P23, pk_mul(N23, P01));
    floatx2 DD  = pk_mul(P01, P23);
    float n8 = __builtin_fmaf(N[0], DD[1], N[1] * DD[0]);
    float d8 = DD[0] * DD[1];
    phi = __builtin_fmaf(n8, __builtin_amdgcn_rcpf(d8), phi);
}

// ---------------------------------------------------------------------------
// main: grid = 4 ig x 32 og x 64 btp = 8192 blocks, block = 128 (2 waves);
// wave w -> o = og*2+w, i in [ig*16, ig*16+16). Per i: ONE mfma_32x32x8
// (K=8 exact) -> C[h(32) x b(32)], issued one iteration ahead of the silu
// that consumes it. RAW W2 slice staged in LDS (broadcast ds_read_b128).
// Loop UNROLLED 2x: per-iteration scheduling overhead (~176 cy idle/iter,
// constant across R1/R2/R5) amortized over two MFMAs; two iterations' silu
// chains interleave. Epilogue: phi * (-1/log2e) (scale cancellation) +
// 1/NIG of b2sum, atomically added to out.
// ---------------------------------------------------------------------------
__global__ __launch_bounds__(128, 6) void main_kernel(
        const f16* __restrict__ w1img, const f16* __restrict__ fimg,
        const float* __restrict__ W2, const float* __restrict__ b2sum,
        float* __restrict__ out) {
    const int tid  = threadIdx.x;
    const int lane = tid & 63;
    const int wv   = tid >> 6;
    const int btp  = blockIdx.x & 63;
    const int og   = (blockIdx.x >> 6) & 31;
    const int ig   = blockIdx.x >> 11;
    const int o    = __builtin_amdgcn_readfirstlane(og * 2 + wv);
    const int p    = lane >> 5;
    const size_t ibase = (size_t)ig * IGW;

    // stage RAW W2 slice: [wave][ii][h] = 2*16*32 floats = 4 KB
    __shared__ float ws2[2][IGW + 1][32];
    {
        int idx = tid * 8;                         // 8 floats per thread
        int wv_ = idx >> 9, ii_ = (idx >> 5) & 15, h_ = idx & 31;
        const float* src = W2 + (ibase + ii_) * 2048
                         + (size_t)(og * 2 + wv_) * 32 + h_;
        *(floatx4*)&ws2[wv_][ii_][h_]     = *(const floatx4*)src;
        *(floatx4*)&ws2[wv_][ii_][h_ + 4] = *(const floatx4*)(src + 4);
    }
    __syncthreads();

    const f16* ap = w1img + ibase * 16384 + ((size_t)o   * 64 + lane) * 4;
    const f16* bp = fimg  + ibase * 16384 + ((size_t)btp * 64 + lane) * 4;

    const floatx16 zeroC = {};
    const floatx2  one2  = {1.0f, 1.0f};
    float phiL = 0.0f, phiH = 0.0f;

    // prologue: frag(0) -> Ccur; frag(1) staged in a_n/b_n
    f16x4 a0v = *(const f16x4*)ap;
    f16x4 b0v = *(const f16x4*)bp;
    f16x4 a_n = *(const f16x4*)(ap + 16384);
    f16x4 b_n = *(const f16x4*)(bp + 16384);
    floatx16 Ccur = __builtin_amdgcn_mfma_f32_32x32x8f16(a0v, b0v, zeroC, 0, 0, 0);

#pragma unroll 2
    for (int ii = 0; ii < IGW; ++ii) {
        // issue next MFMA before consuming Ccur (garbage at ii=IGW-1 — unused)
        floatx16 Cn = __builtin_amdgcn_mfma_f32_32x32x8f16(a_n, b_n, zeroC, 0, 0, 0);
        // prefetch frag(ii+2); tail overruns into the adjacent ws regions —
        // loaded but never consumed, always within the (>=10 MB) workspace
        const size_t i2 = (size_t)(ii + 2);
        a_n = *(const f16x4*)(ap + i2 * 16384);
        b_n = *(const f16x4*)(bp + i2 * 16384);

        const float* wrow = &ws2[wv][ii][p * 4];
        const floatx4 W0 = *(const floatx4*)(wrow);
        const floatx4 W1v = *(const floatx4*)(wrow + 8);
        const floatx4 W2v = *(const floatx4*)(wrow + 16);
        const floatx4 W3v = *(const floatx4*)(wrow + 24);

        // lo half: r = 0,1 ; hi half: r = 2,3
        silu8((floatx2){Ccur[0],  Ccur[1]},  (floatx2){Ccur[4],  Ccur[5]},
              (floatx2){Ccur[8],  Ccur[9]},  (floatx2){Ccur[12], Ccur[13]},
              (floatx2){W0[0], W0[1]}, (floatx2){W1v[0], W1v[1]},
              (floatx2){W2v[0], W2v[1]}, (floatx2){W3v[0], W3v[1]},
              one2, phiL);
        silu8((floatx2){Ccur[2],  Ccur[3]},  (floatx2){Ccur[6],  Ccur[7]},
              (floatx2){Ccur[10], Ccur[11]}, (floatx2){Ccur[14], Ccur[15]},
              (floatx2){W0[2], W0[3]}, (floatx2){W1v[2], W1v[3]},
              (floatx2){W2v[2], W2v[3]}, (floatx2){W3v[2], W3v[3]},
              one2, phiH);

        Ccur = Cn;
    }

    float phi = phiL + phiH;
    // combine the two row-halves (lane and lane^32 share the same column)
    phi += __shfl_xor(phi, 32, 64);

    if (lane < 32) {
        // scale cancellation: accumulated phi = -log2e * sum(a*W2*sigma)
        float v = phi * (-1.0f / LOG2E) + (1.0f / NIG) * b2sum[o];
        unsafeAtomicAdd(out + (size_t)(btp * 32 + lane) * 64 + o, v);
    }
}

extern "C" void kernel_launch(void* const* d_in, const int* in_sizes, int n_in,
                              void* d_out, int out_size, void* d_ws, size_t ws_size,
                              hipStream_t stream) {
    const float* x  = (const float*)d_in[0];
    const float* W1 = (const float*)d_in[1];
    const float* W2 = (const float*)d_in[2];
    const float* B1 = (const float*)d_in[3];
    const float* B2 = (const float*)d_in[4];
    float* out = (float*)d_out;

    // ws: w1img (2MB) | fimg (2MB) | b2sum (256B) | pad (prefetch overrun
    // lands in-bounds: ws_size >= 10 MB per earlier sessions on this problem)
    f16*   w1img = (f16*)d_ws;
    f16*   fimg  = w1img + W1IMG_ELEMS;
    float* b2sum = (float*)(fimg + FIMG_ELEMS);

    prep_kernel<<<1153, 256, 0, stream>>>(W1, B1, B2, x, w1img, fimg, b2sum, out);
    main_kernel<<<NIG * 32 * 64, 128, 0, stream>>>(w1img, fimg, W2, b2sum, out);
}

// Round 10
// 111.435 us; speedup vs baseline: 1.2588x; 1.0035x over previous
//
#include <hip/hip_runtime.h>
#include <math.h>

typedef _Float16 f16;
typedef f16   f16x4    __attribute__((ext_vector_type(4)));
typedef f16   f16x8    __attribute__((ext_vector_type(8)));
typedef float floatx2  __attribute__((ext_vector_type(2)));
typedef float floatx4  __attribute__((ext_vector_type(4)));
typedef float floatx16 __attribute__((ext_vector_type(16)));

#define LOG2E   1.44269504088896340736f
#define INV_2PI 0.15915494309189533577f

// Problem constants
#define B_SZ  2048
#define DIN   64
#define DOUT  64
#define NH    32

#define NIG   4                 // i-groups (8192 blocks)
#define IGW   (DIN / NIG)       // 16 i per block

// Images (built by prep_kernel), K=8-packed for mfma_32x32x8:
//  w1img  f16 [i][o][lane(64)][j(4)]: A1-frag, m=h=lane&31, k=(lane>>5)*4+j.
//         lane<32 -> k=0..3 -> W1[...,{x,s1,s2,s4}]; lane>=32 -> k=4..7 ->
//         {W1[4],W1[5],W1[6],B1}. Scaled by -log2e. MFMA1 -> a'' = -log2e*a.
//  w12img f16: same layout, additionally scaled by W2[i,o,h] per row.
//         MFMA2 -> u'' = -log2e * a * W2 directly (kills the U-muls + the
//         W2 LDS stage in main).
//  fimg   f16 [i][btp(64)][lane(64)][j(4)]: B-frag; lane<32 {x,s1,s2,s4},
//         lane>=32 {c1,c2,c4,1}.
//  b2sum  f32 [64]: column sums of B2.
#define W1IMG_ELEMS ((size_t)DIN * DOUT * 64 * 4)   // 1,048,576 f16 = 2 MB
#define FIMG_ELEMS  ((size_t)DIN * 64 * 64 * 4)     // 1,048,576 f16 = 2 MB

// ---- packed-f32 (VOP3P) helpers ----
__device__ __forceinline__ floatx2 pk_add(floatx2 a, floatx2 b) {
    floatx2 d; asm("v_pk_add_f32 %0, %1, %2" : "=v"(d) : "v"(a), "v"(b)); return d;
}
__device__ __forceinline__ floatx2 pk_mul(floatx2 a, floatx2 b) {
    floatx2 d; asm("v_pk_mul_f32 %0, %1, %2" : "=v"(d) : "v"(a), "v"(b)); return d;
}
__device__ __forceinline__ floatx2 pk_fma(floatx2 a, floatx2 b, floatx2 c) {
    floatx2 d; asm("v_pk_fma_f32 %0, %1, %2, %3" : "=v"(d) : "v"(a), "v"(b), "v"(c)); return d;
}

// ---------------------------------------------------------------------------
// prep: bid [0,512) w1img, [512,1024) w12img, [1024,1536) fimg,
// [1536,1664) zero out[], 1664 b2sum. sin/cos via HW v_sin/v_cos.
// ---------------------------------------------------------------------------
__global__ __launch_bounds__(256) void prep_kernel(
        const float* __restrict__ W1, const float* __restrict__ B1,
        const float* __restrict__ W2, const float* __restrict__ B2,
        const float* __restrict__ x,
        f16* __restrict__ w1img, f16* __restrict__ w12img,
        f16* __restrict__ fimg, float* __restrict__ b2sum,
        float* __restrict__ out) {
    const int bid = blockIdx.x, tid = threadIdx.x;
    if (bid < 1024) {
        const bool second = bid >= 512;
        int u = (second ? bid - 512 : bid) * 256 + tid;  // [i][o][lane2]
        int lane2 = u & 31, o = (u >> 5) & 63, i = u >> 11;
        int l0 = lane2 * 2;
        f16x8 v;
        if (lane2 < 16) {                    // rows l0,l0+1; k=0..3 -> w[0..3]
#pragma unroll
            for (int t = 0; t < 2; ++t) {
                int m = l0 + t;
                float sc = -LOG2E;
                if (second) sc *= W2[(size_t)(i * 64 + o) * 32 + m];
                const float* w = W1 + (size_t)((i * 64 + o) * 32 + m) * 7;
#pragma unroll
                for (int j = 0; j < 4; ++j) v[t * 4 + j] = (f16)(w[j] * sc);
            }
        } else {                             // rows l0-32..; k=4..7 -> w[4..6],B1
#pragma unroll
            for (int t = 0; t < 2; ++t) {
                int m = l0 - 32 + t;
                float sc = -LOG2E;
                if (second) sc *= W2[(size_t)(i * 64 + o) * 32 + m];
                const float* w = W1 + (size_t)((i * 64 + o) * 32 + m) * 7;
                v[t * 4 + 0] = (f16)(w[4] * sc);
                v[t * 4 + 1] = (f16)(w[5] * sc);
                v[t * 4 + 2] = (f16)(w[6] * sc);
                v[t * 4 + 3] = (f16)(B1[(i * 64 + o) * 32 + m] * sc);
            }
        }
        *(f16x8*)((second ? w12img : w1img) + (size_t)u * 8) = v;
    } else if (bid < 1536) {
        int u = (bid - 1024) * 256 + tid;    // [i][btp][lane2]
        int lane2 = u & 31, btp = (u >> 5) & 63, i = u >> 11;
        int l0 = lane2 * 2;
        f16x8 v;
#pragma unroll
        for (int t = 0; t < 2; ++t) {
            int b = btp * 32 + ((l0 + t) & 31);
            float xv = x[b * 64 + i];
            float s1 = __builtin_amdgcn_sinf(xv * INV_2PI);
            float c1 = __builtin_amdgcn_cosf(xv * INV_2PI);
            float s2 = 2.0f * s1 * c1, c2 = 1.0f - 2.0f * s1 * s1;
            float s4 = 2.0f * s2 * c2, c4 = 1.0f - 2.0f * s2 * s2;
            if (lane2 < 16) { v[t*4+0] = (f16)xv; v[t*4+1] = (f16)s1;
                              v[t*4+2] = (f16)s2; v[t*4+3] = (f16)s4; }
            else            { v[t*4+0] = (f16)c1; v[t*4+1] = (f16)c2;
                              v[t*4+2] = (f16)c4; v[t*4+3] = (f16)1.0f; }
        }
        *(f16x8*)(fimg + (size_t)u * 8) = v;
    } else if (bid < 1664) {
        int t = (bid - 1536) * 256 + tid;    // zero out[] (atomics accumulate)
        floatx4 z = {};
        *(floatx4*)(out + (size_t)t * 4) = z;
    } else if (tid < 64) {
        float s = 0.0f;
        for (int i = 0; i < 64; ++i) s += B2[i * 64 + tid];
        b2sum[tid] = s;
    }
}

// silu-sum over 8 activations given preacts A (a'' = -log2e*a) and
// pre-multiplied U (u'' = W2*a'' from MFMA2): 8-way batched reciprocal,
// sum u_i/(1+2^{a_i}) = n8/d8 with ONE rcp. 13 pk + 4 scalar + 9 trans.
__device__ __forceinline__ void silu8(
        floatx2 A0, floatx2 A1, floatx2 A2, floatx2 A3,
        floatx2 U0, floatx2 U1, floatx2 U2, floatx2 U3,
        floatx2 one2, float& phi) {
    floatx2 E0 = {__builtin_amdgcn_exp2f(A0[0]), __builtin_amdgcn_exp2f(A0[1])};
    floatx2 E1 = {__builtin_amdgcn_exp2f(A1[0]), __builtin_amdgcn_exp2f(A1[1])};
    floatx2 E2 = {__builtin_amdgcn_exp2f(A2[0]), __builtin_amdgcn_exp2f(A2[1])};
    floatx2 E3 = {__builtin_amdgcn_exp2f(A3[0]), __builtin_amdgcn_exp2f(A3[1])};
    floatx2 D0 = pk_add(E0, one2), D1 = pk_add(E1, one2);
    floatx2 D2 = pk_add(E2, one2), D3 = pk_add(E3, one2);
    floatx2 N01 = pk_fma(U0, D1, pk_mul(U1, D0));
    floatx2 N23 = pk_fma(U2, D3, pk_mul(U3, D2));
    floatx2 P01 = pk_mul(D0, D1), P23 = pk_mul(D2, D3);
    floatx2 N   = pk_fma(N01, P23, pk_mul(N23, P01));
    floatx2 DD  = pk_mul(P01, P23);
    float n8 = __builtin_fmaf(N[0], DD[1], N[1] * DD[0]);
    float d8 = DD[0] * DD[1];
    phi = __builtin_fmaf(n8, __builtin_amdgcn_rcpf(d8), phi);
}

// ---------------------------------------------------------------------------
// main: grid = 4 ig x 32 og x 64 btp = 8192 blocks, block = 128 (2 waves);
// wave w -> o = og*2+w, i in [ig*16, ig*16+16). Per i: TWO mfma_32x32x8
// sharing the B-frag: MFMA1 -> a''[h,b], MFMA2 (W1*W2 image) -> u''[h,b].
// No LDS, no syncthreads, no C rotation (saturated-issue model: TLP hides
// all latency; only issue-cycles count). silu8 x2 per iter: 26 pk + 8
// scalar + 18 trans. Epilogue: phi * (-1/log2e) + b2sum/NIG, atomic.
// ---------------------------------------------------------------------------
__global__ __launch_bounds__(128, 6) void main_kernel(
        const f16* __restrict__ w1img, const f16* __restrict__ w12img,
        const f16* __restrict__ fimg, const float* __restrict__ b2sum,
        float* __restrict__ out) {
    const int tid  = threadIdx.x;
    const int lane = tid & 63;
    const int wv   = tid >> 6;
    const int btp  = blockIdx.x & 63;
    const int og   = (blockIdx.x >> 6) & 31;
    const int ig   = blockIdx.x >> 11;
    const int o    = __builtin_amdgcn_readfirstlane(og * 2 + wv);
    const size_t ibase = (size_t)ig * IGW;

    const f16* ap1 = w1img  + ibase * 16384 + ((size_t)o   * 64 + lane) * 4;
    const f16* ap2 = w12img + ibase * 16384 + ((size_t)o   * 64 + lane) * 4;
    const f16* bp  = fimg   + ibase * 16384 + ((size_t)btp * 64 + lane) * 4;

    const floatx16 zeroC = {};
    const floatx2  one2  = {1.0f, 1.0f};
    float phiL = 0.0f, phiH = 0.0f;

    // preload frags(0)
    f16x4 fa1 = *(const f16x4*)ap1;
    f16x4 fa2 = *(const f16x4*)ap2;
    f16x4 fb  = *(const f16x4*)bp;

#pragma unroll 1
    for (int ii = 0; ii < IGW; ++ii) {
        floatx16 C1 = __builtin_amdgcn_mfma_f32_32x32x8f16(fa1, fb, zeroC, 0, 0, 0);
        floatx16 C2 = __builtin_amdgcn_mfma_f32_32x32x8f16(fa2, fb, zeroC, 0, 0, 0);

        // prefetch frags(ii+1); at ii=IGW-1 this overruns 16K f16 into the
        // NEXT ws region (w1img->w12img->fimg->pad) — loaded, never consumed,
        // always inside the workspace (layout has >=64 KB slack at the end)
        const size_t i1 = (size_t)(ii + 1);
        fa1 = *(const f16x4*)(ap1 + i1 * 16384);
        fa2 = *(const f16x4*)(ap2 + i1 * 16384);
        fb  = *(const f16x4*)(bp  + i1 * 16384);

        // lo half: r = 0,1 ; hi half: r = 2,3
        silu8((floatx2){C1[0],  C1[1]},  (floatx2){C1[4],  C1[5]},
              (floatx2){C1[8],  C1[9]},  (floatx2){C1[12], C1[13]},
              (floatx2){C2[0],  C2[1]},  (floatx2){C2[4],  C2[5]},
              (floatx2){C2[8],  C2[9]},  (floatx2){C2[12], C2[13]},
              one2, phiL);
        silu8((floatx2){C1[2],  C1[3]},  (floatx2){C1[6],  C1[7]},
              (floatx2){C1[10], C1[11]}, (floatx2){C1[14], C1[15]},
              (floatx2){C2[2],  C2[3]},  (floatx2){C2[6],  C2[7]},
              (floatx2){C2[10], C2[11]}, (floatx2){C2[14], C2[15]},
              one2, phiH);
    }

    float phi = phiL + phiH;
    // combine the two row-halves (lane and lane^32 share the same column)
    phi += __shfl_xor(phi, 32, 64);

    if (lane < 32) {
        // accumulated phi = -log2e * sum(a*W2*sigma(a)) -> scale cancels
        float v = phi * (-1.0f / LOG2E) + (1.0f / NIG) * b2sum[o];
        unsafeAtomicAdd(out + (size_t)(btp * 32 + lane) * 64 + o, v);
    }
}

extern "C" void kernel_launch(void* const* d_in, const int* in_sizes, int n_in,
                              void* d_out, int out_size, void* d_ws, size_t ws_size,
                              hipStream_t stream) {
    const float* x  = (const float*)d_in[0];
    const float* W1 = (const float*)d_in[1];
    const float* W2 = (const float*)d_in[2];
    const float* B1 = (const float*)d_in[3];
    const float* B2 = (const float*)d_in[4];
    float* out = (float*)d_out;

    // ws: w1img (2MB) | w12img (2MB) | fimg (2MB) | b2sum (256B) | pad
    // (tail prefetch overruns land in the next region / pad — in-bounds)
    f16*   w1img  = (f16*)d_ws;
    f16*   w12img = w1img  + W1IMG_ELEMS;
    f16*   fimg   = w12img + W1IMG_ELEMS;
    float* b2sum  = (float*)(fimg + FIMG_ELEMS);

    prep_kernel<<<1665, 256, 0, stream>>>(W1, B1, W2, B2, x,
                                          w1img, w12img, fimg, b2sum, out);
    main_kernel<<<NIG * 32 * 64, 128, 0, stream>>>(w1img, w12img, fimg, b2sum, out);
}